// Round 1
// baseline (647.779 us; speedup 1.0000x reference)
//
#include <hip/hip_runtime.h>
#include <hip/hip_bf16.h>
#include <math.h>

typedef __attribute__((ext_vector_type(8))) short bf16x8s;
typedef __attribute__((ext_vector_type(4))) float f32x4;
typedef __attribute__((ext_vector_type(2))) float f32x2;

#define SEQ 2048
#define NTOK 8192
#define NQKV 3200   // 3072 qkv + 32 ab + 96 zero-pad

static __device__ __forceinline__ float bf2f(unsigned short u) {
  union { unsigned int i; float f; } c; c.i = ((unsigned int)u) << 16; return c.f;
}
static __device__ __forceinline__ unsigned short f2bf(float f) {
  union { float f; unsigned int i; } c; c.f = f;
  unsigned int x = c.i;
  return (unsigned short)((x + 0x7FFFu + ((x >> 16) & 1u)) >> 16);
}

// ---- pure-VALU cross-lane reductions (DPP; no DS ops) ----
static __device__ __forceinline__ float red8(float x) {
  union { float f; int i; } c, d;
  c.f = x; d.i = __builtin_amdgcn_update_dpp(0, c.i, 0xB1, 0xF, 0xF, true); x += d.f;  // quad_perm [1,0,3,2]
  c.f = x; d.i = __builtin_amdgcn_update_dpp(0, c.i, 0x4E, 0xF, 0xF, true); x += d.f;  // quad_perm [2,3,0,1]
  c.f = x; d.i = __builtin_amdgcn_update_dpp(0, c.i, 0x141, 0xF, 0xF, true); x += d.f; // row_half_mirror
  return x;
}
static __device__ __forceinline__ float red16(float x) {
  union { float f; int i; } c, d;
  c.f = x; d.i = __builtin_amdgcn_update_dpp(0, c.i, 0xB1, 0xF, 0xF, true); x += d.f;
  c.f = x; d.i = __builtin_amdgcn_update_dpp(0, c.i, 0x4E, 0xF, 0xF, true); x += d.f;
  c.f = x; d.i = __builtin_amdgcn_update_dpp(0, c.i, 0x141, 0xF, 0xF, true); x += d.f;
  c.f = x; d.i = __builtin_amdgcn_update_dpp(0, c.i, 0x140, 0xF, 0xF, true); x += d.f; // row_mirror
  return x;
}

// ---------------------------------------------------------------- x cast fp32 -> bf16
__global__ __launch_bounds__(256) void castx_k(const float* __restrict__ in,
                                               unsigned short* __restrict__ out, int n4) {
  int i = blockIdx.x * 256 + threadIdx.x;
  if (i >= n4) return;
  float4 v = ((const float4*)in)[i];
  ushort4 o;
  o.x = f2bf(v.x); o.y = f2bf(v.y); o.z = f2bf(v.z); o.w = f2bf(v.w);
  ((ushort4*)out)[i] = o;
}

// ---------------------------------------------------------------- transpose fp32 -> bf16
__global__ void transpose_k(const float* __restrict__ in,
                            unsigned short* __restrict__ out, int R, int C) {
  __shared__ unsigned short tile[32][33];
  int c0 = blockIdx.x * 32, r0 = blockIdx.y * 32;
  int tx = threadIdx.x, ty = threadIdx.y;
  for (int i = ty; i < 32; i += 8)
    tile[i][tx] = f2bf(in[(size_t)(r0 + i) * C + c0 + tx]);
  __syncthreads();
  for (int i = ty; i < 32; i += 8)
    out[(size_t)(c0 + i) * R + r0 + tx] = tile[tx][i];
}

// ---------------------------------------------------------------- Wab^T rows (bf16) + zero pad
__global__ void build_wabT(const float* __restrict__ Wa,
                           const float* __restrict__ Wb,
                           unsigned short* __restrict__ rows) {
  int i = blockIdx.x * 256 + threadIdx.x;  // 128 * 1024
  int j = i >> 10, k = i & 1023;
  float v = 0.f;
  if (j < 16) v = Wa[k * 16 + j];
  else if (j < 32) v = Wb[k * 16 + (j - 16)];
  rows[(size_t)j * 1024 + k] = f2bf(v);
}

// ---------------------------------------------------------------- MFMA GEMM (m97 staging)
// C[M,N] = A[M,K] * Bt[N,K]^T. MODE 0: bf16 out; 1: f32 out;
// 2: fused qkv: per-head l2norm for cols<2048, sigmoid alpha/beta for 3072..3103.
template<int MODE>
__global__ __launch_bounds__(256) void gemm_bt(const unsigned short* __restrict__ A,
                                               const unsigned short* __restrict__ Bt,
                                               void* __restrict__ Cv,
                                               int M, int N, int K,
                                               const float* __restrict__ ba,
                                               const float* __restrict__ bbp,
                                               float* __restrict__ alphaF,
                                               float* __restrict__ betaF) {
  __shared__ __align__(16) unsigned short As[128 * 32];
  __shared__ __align__(16) unsigned short Bs[128 * 32];
  int tiles_n = N >> 7;
  int tm = blockIdx.x / tiles_n, tn = blockIdx.x % tiles_n;
  int m0 = tm << 7, n0 = tn << 7;
  int tid = threadIdx.x;
  int wave = tid >> 6, lane = tid & 63;
  int wm = wave >> 1, wn = wave & 1;
  int r = lane & 15, qd = lane >> 4;
  int lr = lane >> 2, lc = lane & 3;

  f32x4 acc[4][4];
#pragma unroll
  for (int mi = 0; mi < 4; mi++)
#pragma unroll
    for (int ni = 0; ni < 4; ni++) acc[mi][ni] = (f32x4){0.f, 0.f, 0.f, 0.f};

  for (int k0 = 0; k0 < K; k0 += 32) {
#pragma unroll
    for (int gi = 0; gi < 2; ++gi) {
      int g = wave + gi * 4;
      int row = g * 16 + lr;
      const unsigned short* ga = A + (size_t)(m0 + row) * K + k0 + lc * 8;
      const unsigned short* gb = Bt + (size_t)(n0 + row) * K + k0 + lc * 8;
      __builtin_amdgcn_global_load_lds(
          (const __attribute__((address_space(1))) unsigned int*)ga,
          (__attribute__((address_space(3))) unsigned int*)(As + g * 512 + lane * 8),
          16, 0, 0);
      __builtin_amdgcn_global_load_lds(
          (const __attribute__((address_space(1))) unsigned int*)gb,
          (__attribute__((address_space(3))) unsigned int*)(Bs + g * 512 + lane * 8),
          16, 0, 0);
    }
    __syncthreads();
    bf16x8s af[4], bfr[4];
#pragma unroll
    for (int mi = 0; mi < 4; mi++)
      af[mi] = *(const bf16x8s*)&As[(wm * 64 + mi * 16 + r) * 32 + qd * 8];
#pragma unroll
    for (int ni = 0; ni < 4; ni++)
      bfr[ni] = *(const bf16x8s*)&Bs[(wn * 64 + ni * 16 + r) * 32 + qd * 8];
#pragma unroll
    for (int mi = 0; mi < 4; mi++)
#pragma unroll
      for (int ni = 0; ni < 4; ni++)
        acc[mi][ni] = __builtin_amdgcn_mfma_f32_16x16x32_bf16(af[mi], bfr[ni], acc[mi][ni], 0, 0, 0);
    __syncthreads();
  }

  bool qk = (MODE == 2) && (n0 < 2048);  // wave's 64-col block == one head
#pragma unroll
  for (int mi = 0; mi < 4; mi++) {
    f32x4 sc = (f32x4){1.f, 1.f, 1.f, 1.f};
    if (qk) {
      f32x4 ss = acc[mi][0] * acc[mi][0] + acc[mi][1] * acc[mi][1]
               + acc[mi][2] * acc[mi][2] + acc[mi][3] * acc[mi][3];
#pragma unroll
      for (int cc = 0; cc < 4; cc++) {
        float s = red16(ss[cc]);
        sc[cc] = 1.f / fmaxf(sqrtf(s), 1e-12f);
      }
    }
#pragma unroll
    for (int ni = 0; ni < 4; ni++)
#pragma unroll
      for (int reg = 0; reg < 4; reg++) {
        int m = m0 + wm * 64 + mi * 16 + qd * 4 + reg;
        int n = n0 + wn * 64 + ni * 16 + r;
        float a = acc[mi][ni][reg];
        if (MODE == 0) ((unsigned short*)Cv)[(size_t)m * N + n] = f2bf(a);
        else if (MODE == 1) ((float*)Cv)[(size_t)m * N + n] = a;
        else {
          if (qk) a *= sc[reg];
          if (n < 3072) ((unsigned short*)Cv)[(size_t)m * 3072 + n] = f2bf(a);
          else if (n < 3104) {
            int j = n - 3072;
            float bias = (j < 16) ? ba[j] : bbp[j - 16];
            float s = 1.f / (1.f + expf(-(a + bias)));
            if (j < 16) alphaF[(size_t)m * 16 + j] = s;
            else        betaF[(size_t)m * 16 + (j - 16)] = s;
          }
        }
      }
  }
}

// ---------------------------------------------------------------- scan
// 512 blocks = (b*16+h)*8 + ec; block = 64 thr (ONE wave).
// lane = el*8+g: el = local e, g = d-octet. 8 fp32 S regs/lane (as 4x f32x2).
//
// 1-step LOOKAHEAD: the serial chain  c_{t-1} -> S_{t-1} -> dot -> red8 -> pr_t -> c_t
// is split across two iterations.  At iter t (state S = S_{t-1}) we compute
//   uN = S_{t-1}.k_{t+1},  wN = S_{t-1}.q_{t+1}   (dot + red8, consumed NEXT iter)
// and use last iter's results via the exact rank-1 correction
//   pr_t = a_{t-1}*uP + c_{t-1}*kk_t,   kk_t  = k_{t-1}.k_t   (precomputed/chunk)
//   qs_t = a_{t-1}*wP + c_{t-1}*kq1_t,  kq1_t = k_{t-1}.q_t   (precomputed/chunk)
// leaving a 2-FMA/step scalar critical path. Chunk boundaries: pr/qs of the
// first step are taken directly from the boundary dot (cP=0, aP=1).
#define TC 32
#define NCH (SEQ / TC)
#define LK 0
#define LQ 2048
#define LV 4096          // stores b_t * v_t[e]
#define LABQ 4352        // per t (stride 8): [a, b, kq0, kk, kq1, -, -, -]
#define SBUF 4608

static __device__ __forceinline__ void unpack8(uint4 v, float* f) {
  f[0] = bf2f((unsigned short)(v.x & 0xffff)); f[1] = bf2f((unsigned short)(v.x >> 16));
  f[2] = bf2f((unsigned short)(v.y & 0xffff)); f[3] = bf2f((unsigned short)(v.y >> 16));
  f[4] = bf2f((unsigned short)(v.z & 0xffff)); f[5] = bf2f((unsigned short)(v.z >> 16));
  f[6] = bf2f((unsigned short)(v.w & 0xffff)); f[7] = bf2f((unsigned short)(v.w >> 16));
}

struct Pref { uint4 k8[4], q8[4], v8; float ab; };

static __device__ __forceinline__ Pref scan_load(const unsigned short* __restrict__ qkv,
                                                 const float* __restrict__ alphaF,
                                                 const float* __restrict__ betaF,
                                                 int b, int h, int ec, int t0, int tid) {
  Pref p; p.v8 = (uint4){0, 0, 0, 0};
  const unsigned short* base = qkv + (size_t)(b * SEQ + t0) * 3072 + h * 64;
#pragma unroll
  for (int j = 0; j < 4; ++j) {
    int idx = j * 64 + tid;          // t*8 + seg
    int t = idx >> 3, seg = idx & 7;
    p.q8[j] = *(const uint4*)(base + (size_t)t * 3072 + seg * 8);
    p.k8[j] = *(const uint4*)(base + (size_t)t * 3072 + 1024 + seg * 8);
  }
  if (tid < 32) {
    p.v8 = *(const uint4*)(base + (size_t)tid * 3072 + 2048 + ec * 8);
    p.ab = alphaF[(size_t)(b * SEQ + t0 + tid) * 16 + h];
  } else {
    p.ab = betaF[(size_t)(b * SEQ + t0 + (tid - 32)) * 16 + h];
  }
  return p;
}

static __device__ __forceinline__ float dot8s(float4 a0, float4 a1, float4 b0, float4 b1) {
  return ((a0.x * b0.x + a0.y * b0.y) + (a0.z * b0.z + a0.w * b0.w))
       + ((a1.x * b1.x + a1.y * b1.y) + (a1.z * b1.z + a1.w * b1.w));
}

static __device__ __forceinline__ float dot8v(f32x2 S01, f32x2 S23, f32x2 S45, f32x2 S67,
                                              float4 x0, float4 x1) {
  f32x2 X01 = {x0.x, x0.y}, X23 = {x0.z, x0.w}, X45 = {x1.x, x1.y}, X67 = {x1.z, x1.w};
  f32x2 t1 = S01 * X01 + S23 * X23;
  f32x2 t2 = S45 * X45 + S67 * X67;
  f32x2 s = t1 + t2;
  return s.x + s.y;
}

// phase 1: stage k,q,bv,a,b,kq0 into LDS. phase 2 (after barrier): cross-step
// dots kk_t = k_{t-1}.k_t and kq1_t = k_{t-1}.q_t (t=0 -> 0).
static __device__ __forceinline__ void scan_store(float* __restrict__ buf, const Pref& p, int tid) {
#pragma unroll
  for (int j = 0; j < 4; ++j) {
    int idx = j * 64 + tid;
    int t = idx >> 3, seg = idx & 7;
    float kf[8], qf[8];
    unpack8(p.k8[j], kf);
    unpack8(p.q8[j], qf);
    *(float4*)&buf[LK + t * 64 + seg * 8]     = (float4){kf[0], kf[1], kf[2], kf[3]};
    *(float4*)&buf[LK + t * 64 + seg * 8 + 4] = (float4){kf[4], kf[5], kf[6], kf[7]};
    *(float4*)&buf[LQ + t * 64 + seg * 8]     = (float4){qf[0], qf[1], qf[2], qf[3]};
    *(float4*)&buf[LQ + t * 64 + seg * 8 + 4] = (float4){qf[4], qf[5], qf[6], qf[7]};
    float s = kf[0]*qf[0] + kf[1]*qf[1] + kf[2]*qf[2] + kf[3]*qf[3]
            + kf[4]*qf[4] + kf[5]*qf[5] + kf[6]*qf[6] + kf[7]*qf[7];
    s = red8(s);
    if ((tid & 7) == 0) buf[LABQ + t * 8 + 2] = s;   // kq0_t
  }
  float btv = __shfl(p.ab, tid | 32);                 // beta_t for lane t (t = tid&31)
  if (tid < 32) {
    float vf[8];
    unpack8(p.v8, vf);
    *(float4*)&buf[LV + tid * 8]     = (float4){btv*vf[0], btv*vf[1], btv*vf[2], btv*vf[3]};
    *(float4*)&buf[LV + tid * 8 + 4] = (float4){btv*vf[4], btv*vf[5], btv*vf[6], btv*vf[7]};
    buf[LABQ + tid * 8 + 0] = p.ab;                  // alpha_t
  } else {
    buf[LABQ + (tid - 32) * 8 + 1] = p.ab;           // beta_t
  }
  __syncthreads();
#pragma unroll
  for (int j = 0; j < 4; ++j) {
    int idx = j * 64 + tid;
    int t = idx >> 3, seg = idx & 7;
    float4 kc0 = *(const float4*)&buf[LK + t * 64 + seg * 8];
    float4 kc1 = *(const float4*)&buf[LK + t * 64 + seg * 8 + 4];
    float4 qc0 = *(const float4*)&buf[LQ + t * 64 + seg * 8];
    float4 qc1 = *(const float4*)&buf[LQ + t * 64 + seg * 8 + 4];
    float4 kp0 = (float4){0.f, 0.f, 0.f, 0.f}, kp1 = kp0;
    if (t > 0) {
      kp0 = *(const float4*)&buf[LK + (t - 1) * 64 + seg * 8];
      kp1 = *(const float4*)&buf[LK + (t - 1) * 64 + seg * 8 + 4];
    }
    float skk = red8(dot8s(kp0, kp1, kc0, kc1));
    float skq = red8(dot8s(kp0, kp1, qc0, qc1));
    if ((tid & 7) == 0) {
      buf[LABQ + t * 8 + 3] = skk;                   // kk_t
      buf[LABQ + t * 8 + 4] = skq;                   // kq1_t
    }
  }
}

#define LOADSLOT(BB, I, TT) do {                                        \
    rk0[I]  = *(const float4*)&(BB)[LK + (TT) * 64 + g * 8];            \
    rk1[I]  = *(const float4*)&(BB)[LK + (TT) * 64 + g * 8 + 4];        \
    rq0[I]  = *(const float4*)&(BB)[LQ + (TT) * 64 + g * 8];            \
    rq1[I]  = *(const float4*)&(BB)[LQ + (TT) * 64 + g * 8 + 4];        \
    rabq[I] = *(const float4*)&(BB)[LABQ + (TT) * 8];                   \
    rkq1[I] = (BB)[LABQ + (TT) * 8 + 4];                                \
    rbv[I]  = (BB)[LV + (TT) * 8 + el];                                 \
  } while (0)

__global__ __launch_bounds__(64) void scan_k(const unsigned short* __restrict__ qkv,
                                             const float* __restrict__ alphaF,
                                             const float* __restrict__ betaF,
                                             unsigned short* __restrict__ y) {
  __shared__ float sm[2 * SBUF];  // 36.9 KB
  int bh = blockIdx.x >> 3, ec = blockIdx.x & 7;
  int b = bh >> 4, h = bh & 15;
  int tid = threadIdx.x;
  int el = tid >> 3;
  int g = tid & 7;

  f32x2 S01 = {0.f, 0.f}, S23 = {0.f, 0.f}, S45 = {0.f, 0.f}, S67 = {0.f, 0.f};

  Pref p = scan_load(qkv, alphaF, betaF, b, h, ec, 0, tid);
  scan_store(sm, p, tid);
  __syncthreads();

  float4 rk0[2], rk1[2], rq0[2], rq1[2], rabq[2];
  float rkq1[2], rbv[2];
  LOADSLOT(sm, 0, 0);
  LOADSLOT(sm, 1, 1);
  float uP = 0.f, wP = 0.f, cP = 0.f, aP = 0.f;

  unsigned short* yb = y + (size_t)(b * SEQ) * 1024 + h * 64 + ec * 8 + el;

  for (int c = 0; c < NCH; ++c) {
    if (c + 1 < NCH)
      p = scan_load(qkv, alphaF, betaF, b, h, ec, (c + 1) * TC, tid);

    const float* bb = sm + (c & 1) * SBUF;
    float yo[TC];
#pragma unroll
    for (int t = 0; t < TC; ++t) {
      const int sl = t & 1;
      float4 k0 = rk0[sl], k1 = rk1[sl];
      float4 abq = rabq[sl];
      float kq1v = rkq1[sl], bv = rbv[sl];
      float a = abq.x, bt = abq.y, kq0 = abq.z, kk = abq.w;
      if (t + 2 < TC) LOADSLOT(bb, sl, t + 2);
      // lookahead dots against t+1, with S = S_{t-1} (pre-update)
      float uN = 0.f, wN = 0.f;
      if (t + 1 < TC) {
        const int so = sl ^ 1;
        uN = red8(dot8v(S01, S23, S45, S67, rk0[so], rk1[so]));
        wN = red8(dot8v(S01, S23, S45, S67, rq0[so], rq1[so]));
      }
      // current-step scalars via rank-1 correction (2-FMA chain)
      float pr = fmaf(aP, uP, cP * kk);
      float qs = fmaf(aP, wP, cP * kq1v);
      float cc = fmaf(-bt, pr, bv);        // b*(v - pr)
      yo[t] = fmaf(a, qs, cc * kq0);
      // state update: S = a*S + cc*k   (a*S issued early, chain from cc = 1 fma)
      f32x2 a2; a2.x = a; a2.y = a;
      f32x2 c2; c2.x = cc; c2.y = cc;
      f32x2 aS0 = a2 * S01, aS1 = a2 * S23, aS2 = a2 * S45, aS3 = a2 * S67;
      f32x2 K01 = {k0.x, k0.y}, K23 = {k0.z, k0.w}, K45 = {k1.x, k1.y}, K67 = {k1.z, k1.w};
      S01 = c2 * K01 + aS0;
      S23 = c2 * K23 + aS1;
      S45 = c2 * K45 + aS2;
      S67 = c2 * K67 + aS3;
      uP = uN; wP = wN; cP = cc; aP = a;
    }
    if (g == 0) {
#pragma unroll
      for (int t = 0; t < TC; ++t)
        yb[(size_t)(c * TC + t) * 1024] = f2bf(yo[t]);
    }
    if (c + 1 < NCH) {
      float* nb = sm + ((c + 1) & 1) * SBUF;
      scan_store(nb, p, tid);
      __syncthreads();
      LOADSLOT(nb, 0, 0);
      LOADSLOT(nb, 1, 1);
      // boundary: pr/qs of next chunk's t=0 come straight from these dots
      uP = red8(dot8v(S01, S23, S45, S67, rk0[0], rk1[0]));
      wP = red8(dot8v(S01, S23, S45, S67, rq0[0], rq1[0]));
      cP = 0.f; aP = 1.f;
    }
  }
}

// ---------------------------------------------------------------- rmsnorm*gate
__global__ __launch_bounds__(256) void rmsgate_k(const unsigned short* __restrict__ y,
                                                 const unsigned short* __restrict__ gl,
                                                 const float* __restrict__ gnorm,
                                                 unsigned short* __restrict__ z) {
  __shared__ float red[4];
  int row = blockIdx.x, tid = threadIdx.x;
  size_t base = (size_t)row * 1024 + tid * 4;
  uint2 yv = *(const uint2*)&y[base];
  float f0 = bf2f((unsigned short)(yv.x & 0xffff)), f1 = bf2f((unsigned short)(yv.x >> 16));
  float f2 = bf2f((unsigned short)(yv.y & 0xffff)), f3 = bf2f((unsigned short)(yv.y >> 16));
  float ss = f0 * f0 + f1 * f1 + f2 * f2 + f3 * f3;
#pragma unroll
  for (int s = 1; s < 64; s <<= 1) ss += __shfl_xor(ss, s);
  if ((tid & 63) == 0) red[tid >> 6] = ss;
  __syncthreads();
  ss = red[0] + red[1] + red[2] + red[3];
  float rms = rsqrtf(ss * (1.0f / 1024.0f) + 1e-5f);
  uint2 gv = *(const uint2*)&gl[base];
  float4 gn = *(const float4*)&gnorm[tid * 4];
  float g[4] = {bf2f((unsigned short)(gv.x & 0xffff)), bf2f((unsigned short)(gv.x >> 16)),
                bf2f((unsigned short)(gv.y & 0xffff)), bf2f((unsigned short)(gv.y >> 16))};
  float gnv[4] = {gn.x, gn.y, gn.z, gn.w};
  float fv[4] = {f0, f1, f2, f3};
  unsigned short o[4];
#pragma unroll
  for (int jj = 0; jj < 4; jj++) {
    float gate = g[jj] / (1.f + expf(-g[jj]));  // silu
    o[jj] = f2bf(fv[jj] * rms * gnv[jj] * gate);
  }
  uint2 ov;
  ov.x = (unsigned int)o[0] | ((unsigned int)o[1] << 16);
  ov.y = (unsigned int)o[2] | ((unsigned int)o[3] << 16);
  *(uint2*)&z[base] = ov;
}

// ---------------------------------------------------------------- launch
extern "C" void kernel_launch(void* const* d_in, const int* in_sizes, int n_in,
                              void* d_out, int out_size, void* d_ws, size_t ws_size,
                              hipStream_t stream) {
  const float* x     = (const float*)d_in[0];
  const float* Wq    = (const float*)d_in[1];
  const float* Wk    = (const float*)d_in[2];
  const float* Wv    = (const float*)d_in[3];
  const float* Wa    = (const float*)d_in[4];
  const float* ba    = (const float*)d_in[5];
  const float* Wb    = (const float*)d_in[6];
  const float* bb    = (const float*)d_in[7];
  const float* Wg    = (const float*)d_in[8];
  const float* Wo    = (const float*)d_in[9];
  const float* gnorm = (const float*)d_in[10];
  float* out = (float*)d_out;

  unsigned short* xbf    = (unsigned short*)d_ws;                 // 8192*1024
  unsigned short* Bt_qkv = xbf + (size_t)NTOK * 1024;             // 3200*1024
  unsigned short* Bt_g   = Bt_qkv + (size_t)NQKV * 1024;          // 1024*1024
  unsigned short* Bt_o   = Bt_g + (size_t)1024 * 1024;            // 1024*1024
  unsigned short* qkv    = Bt_o + (size_t)1024 * 1024;            // 8192*3072
  unsigned short* gatelin= qkv + (size_t)NTOK * 3072;             // 8192*1024
  unsigned short* ybuf   = gatelin + (size_t)NTOK * 1024;         // 8192*1024
  float* alphaF          = (float*)(ybuf + (size_t)NTOK * 1024);  // 8192*16
  float* betaF           = alphaF + (size_t)NTOK * 16;            // 8192*16
  unsigned short* zbuf   = xbf;  // alias: xbf dead after gate GEMM

  castx_k<<<NTOK * 1024 / 4 / 256, 256, 0, stream>>>(x, xbf, NTOK * 1024 / 4);
  dim3 tb(32, 8);
  transpose_k<<<dim3(32, 32), tb, 0, stream>>>(Wq, Bt_qkv, 1024, 1024);
  transpose_k<<<dim3(32, 32), tb, 0, stream>>>(Wk, Bt_qkv + (size_t)1024 * 1024, 1024, 1024);
  transpose_k<<<dim3(32, 32), tb, 0, stream>>>(Wv, Bt_qkv + (size_t)2048 * 1024, 1024, 1024);
  transpose_k<<<dim3(32, 32), tb, 0, stream>>>(Wg, Bt_g, 1024, 1024);
  transpose_k<<<dim3(32, 32), tb, 0, stream>>>(Wo, Bt_o, 1024, 1024);
  build_wabT<<<512, 256, 0, stream>>>(Wa, Wb, Bt_qkv + (size_t)3072 * 1024);

  gemm_bt<2><<<(NTOK / 128) * (NQKV / 128), 256, 0, stream>>>(
      xbf, Bt_qkv, qkv, NTOK, NQKV, 1024, ba, bb, alphaF, betaF);
  gemm_bt<0><<<(NTOK / 128) * (1024 / 128), 256, 0, stream>>>(
      xbf, Bt_g, gatelin, NTOK, 1024, 1024, nullptr, nullptr, nullptr, nullptr);
  scan_k<<<512, 64, 0, stream>>>(qkv, alphaF, betaF, ybuf);
  rmsgate_k<<<NTOK, 256, 0, stream>>>(ybuf, gatelin, gnorm, zbuf);
  gemm_bt<1><<<(NTOK / 128) * (1024 / 128), 256, 0, stream>>>(
      zbuf, Bt_o, out, NTOK, 1024, 1024, nullptr, nullptr, nullptr, nullptr);
}

// Round 2
// 538.276 us; speedup vs baseline: 1.2034x; 1.2034x over previous
//
#include <hip/hip_runtime.h>
#include <hip/hip_bf16.h>
#include <math.h>

typedef __attribute__((ext_vector_type(8))) short bf16x8s;
typedef __attribute__((ext_vector_type(4))) float f32x4;

#define SEQ 2048
#define NTOK 8192
#define NQKV 3200   // 3072 qkv + 32 ab + 96 zero-pad

static __device__ __forceinline__ float bf2f(unsigned short u) {
  union { unsigned int i; float f; } c; c.i = ((unsigned int)u) << 16; return c.f;
}
static __device__ __forceinline__ unsigned short f2bf(float f) {
  union { float f; unsigned int i; } c; c.f = f;
  unsigned int x = c.i;
  return (unsigned short)((x + 0x7FFFu + ((x >> 16) & 1u)) >> 16);
}

static __device__ __forceinline__ float red16(float x) {
  union { float f; int i; } c, d;
  c.f = x; d.i = __builtin_amdgcn_update_dpp(0, c.i, 0xB1, 0xF, 0xF, true); x += d.f;
  c.f = x; d.i = __builtin_amdgcn_update_dpp(0, c.i, 0x4E, 0xF, 0xF, true); x += d.f;
  c.f = x; d.i = __builtin_amdgcn_update_dpp(0, c.i, 0x141, 0xF, 0xF, true); x += d.f;
  c.f = x; d.i = __builtin_amdgcn_update_dpp(0, c.i, 0x140, 0xF, 0xF, true); x += d.f;
  return x;
}

// ---------------------------------------------------------------- x cast fp32 -> bf16
__global__ __launch_bounds__(256) void castx_k(const float* __restrict__ in,
                                               unsigned short* __restrict__ out, int n4) {
  int i = blockIdx.x * 256 + threadIdx.x;
  if (i >= n4) return;
  float4 v = ((const float4*)in)[i];
  ushort4 o;
  o.x = f2bf(v.x); o.y = f2bf(v.y); o.z = f2bf(v.z); o.w = f2bf(v.w);
  ((ushort4*)out)[i] = o;
}

// ---------------------------------------------------------------- transpose fp32 -> bf16
__global__ void transpose_k(const float* __restrict__ in,
                            unsigned short* __restrict__ out, int R, int C) {
  __shared__ unsigned short tile[32][33];
  int c0 = blockIdx.x * 32, r0 = blockIdx.y * 32;
  int tx = threadIdx.x, ty = threadIdx.y;
  for (int i = ty; i < 32; i += 8)
    tile[i][tx] = f2bf(in[(size_t)(r0 + i) * C + c0 + tx]);
  __syncthreads();
  for (int i = ty; i < 32; i += 8)
    out[(size_t)(c0 + i) * R + r0 + tx] = tile[tx][i];
}

// ---------------------------------------------------------------- Wab^T rows (bf16) + zero pad
__global__ void build_wabT(const float* __restrict__ Wa,
                           const float* __restrict__ Wb,
                           unsigned short* __restrict__ rows) {
  int i = blockIdx.x * 256 + threadIdx.x;  // 128 * 1024
  int j = i >> 10, k = i & 1023;
  float v = 0.f;
  if (j < 16) v = Wa[k * 16 + j];
  else if (j < 32) v = Wb[k * 16 + (j - 16)];
  rows[(size_t)j * 1024 + k] = f2bf(v);
}

// ---------------------------------------------------------------- MFMA GEMM (m97 staging)
template<int MODE>
__global__ __launch_bounds__(256) void gemm_bt(const unsigned short* __restrict__ A,
                                               const unsigned short* __restrict__ Bt,
                                               void* __restrict__ Cv,
                                               int M, int N, int K,
                                               const float* __restrict__ ba,
                                               const float* __restrict__ bbp,
                                               float* __restrict__ alphaF,
                                               float* __restrict__ betaF) {
  __shared__ __align__(16) unsigned short As[128 * 32];
  __shared__ __align__(16) unsigned short Bs[128 * 32];
  int tiles_n = N >> 7;
  int tm = blockIdx.x / tiles_n, tn = blockIdx.x % tiles_n;
  int m0 = tm << 7, n0 = tn << 7;
  int tid = threadIdx.x;
  int wave = tid >> 6, lane = tid & 63;
  int wm = wave >> 1, wn = wave & 1;
  int r = lane & 15, qd = lane >> 4;
  int lr = lane >> 2, lc = lane & 3;

  f32x4 acc[4][4];
#pragma unroll
  for (int mi = 0; mi < 4; mi++)
#pragma unroll
    for (int ni = 0; ni < 4; ni++) acc[mi][ni] = (f32x4){0.f, 0.f, 0.f, 0.f};

  for (int k0 = 0; k0 < K; k0 += 32) {
#pragma unroll
    for (int gi = 0; gi < 2; ++gi) {
      int g = wave + gi * 4;
      int row = g * 16 + lr;
      const unsigned short* ga = A + (size_t)(m0 + row) * K + k0 + lc * 8;
      const unsigned short* gb = Bt + (size_t)(n0 + row) * K + k0 + lc * 8;
      __builtin_amdgcn_global_load_lds(
          (const __attribute__((address_space(1))) unsigned int*)ga,
          (__attribute__((address_space(3))) unsigned int*)(As + g * 512 + lane * 8),
          16, 0, 0);
      __builtin_amdgcn_global_load_lds(
          (const __attribute__((address_space(1))) unsigned int*)gb,
          (__attribute__((address_space(3))) unsigned int*)(Bs + g * 512 + lane * 8),
          16, 0, 0);
    }
    __syncthreads();
    bf16x8s af[4], bfr[4];
#pragma unroll
    for (int mi = 0; mi < 4; mi++)
      af[mi] = *(const bf16x8s*)&As[(wm * 64 + mi * 16 + r) * 32 + qd * 8];
#pragma unroll
    for (int ni = 0; ni < 4; ni++)
      bfr[ni] = *(const bf16x8s*)&Bs[(wn * 64 + ni * 16 + r) * 32 + qd * 8];
#pragma unroll
    for (int mi = 0; mi < 4; mi++)
#pragma unroll
      for (int ni = 0; ni < 4; ni++)
        acc[mi][ni] = __builtin_amdgcn_mfma_f32_16x16x32_bf16(af[mi], bfr[ni], acc[mi][ni], 0, 0, 0);
    __syncthreads();
  }

  bool qk = (MODE == 2) && (n0 < 2048);
#pragma unroll
  for (int mi = 0; mi < 4; mi++) {
    f32x4 sc = (f32x4){1.f, 1.f, 1.f, 1.f};
    if (qk) {
      f32x4 ss = acc[mi][0] * acc[mi][0] + acc[mi][1] * acc[mi][1]
               + acc[mi][2] * acc[mi][2] + acc[mi][3] * acc[mi][3];
#pragma unroll
      for (int cc = 0; cc < 4; cc++) {
        float s = red16(ss[cc]);
        sc[cc] = 1.f / fmaxf(sqrtf(s), 1e-12f);
      }
    }
#pragma unroll
    for (int ni = 0; ni < 4; ni++)
#pragma unroll
      for (int reg = 0; reg < 4; reg++) {
        int m = m0 + wm * 64 + mi * 16 + qd * 4 + reg;
        int n = n0 + wn * 64 + ni * 16 + r;
        float a = acc[mi][ni][reg];
        if (MODE == 0) ((unsigned short*)Cv)[(size_t)m * N + n] = f2bf(a);
        else if (MODE == 1) ((float*)Cv)[(size_t)m * N + n] = a;
        else {
          if (qk) a *= sc[reg];
          if (n < 3072) ((unsigned short*)Cv)[(size_t)m * 3072 + n] = f2bf(a);
          else if (n < 3104) {
            int j = n - 3072;
            float bias = (j < 16) ? ba[j] : bbp[j - 16];
            float s = 1.f / (1.f + expf(-(a + bias)));
            if (j < 16) alphaF[(size_t)m * 16 + j] = s;
            else        betaF[(size_t)m * 16 + (j - 16)] = s;
          }
        }
      }
  }
}

// ================================================================ chunked delta-rule scan
// 64 blocks = (b,h); 512 thr = 8 waves. Chunk L=32, NC=64 chunks sequential.
// Math per chunk (S_in = state, d x e):
//   e_t = prod_{s<=t} a_s ; W = K*S_in ; U = Q*S_in (MFMA, hi/lo bf16 S)
//   D_t = b_t v_t - b_t e_{t-1} W_t
//   M[t][i] = b_t (e_{t-1}/e_i)(k_i.k_t), i<t ; c_t = D_t - sum_{i<t} M[t][i] c_i  (fwd-sub, 2-op chain)
//   G[t][i] = (e_t/e_i)(k_i.q_t), i<=t ; y_t = e_t U_t + (G*C)_t
//   S_out = e31 S_in + KT' * C  where KT'[d][i] = k_i[d]*(e31/e_i)
#define D_OFF_STHI 0        // bf16 [64 e][64 d]  swz   8192
#define D_OFF_STLO 8192     //                         8192
#define D_OFF_K    16384    // bf16 [2][32 t][64 d] swz 8192
#define D_OFF_Q    24576    //                         8192
#define D_OFF_V    32768    // bf16 [2][32 t][64 e] swz 8192
#define D_OFF_KT   40960    // bf16 [64 d][32 i] scaled 4096
#define D_OFF_MT   45056    // f32 [2][32 i][32 t]     8192
#define D_OFF_GBF  53248    // bf16 [2][32 t][32 i]    4096
#define D_OFF_CTHI 57344    // bf16 [2][64 e][40 i]   10240
#define D_OFF_CTLO 67584    //                        10240
#define D_OFF_W    77824    // f32 [32 t][64 e]        8192
#define D_OFF_U    86016    // f32 [2][32 t][64 e]    16384
#define D_OFF_AB   102400   // f32 [4][132]            2112
#define D_LDS_SIZE 104512
// ab slot layout (floats): EPREV 0..31, EINC 32..63, EINV 64..95, B 96..127, E31 128

static __device__ __forceinline__ float rdlane(float v, int i) {
  return __int_as_float(__builtin_amdgcn_readlane(__float_as_int(v), i));
}

__global__ __launch_bounds__(512, 2) void dscan_k(const unsigned short* __restrict__ qkv,
                                                  const float* __restrict__ alphaF,
                                                  const float* __restrict__ betaF,
                                                  unsigned short* __restrict__ y) {
  extern __shared__ char smem[];
  const int bh = blockIdx.x;
  const int b = bh >> 4, h = bh & 15;
  const int tid = threadIdx.x, wid = tid >> 6, lane = tid & 63;
  const int r = lane & 15, qd = lane >> 4;

  float* abf = (float*)(smem + D_OFF_AB);

  // --------- helpers as macros/lambdas ----------
  auto stage_jobs = [&](int cn) {
    int buf = cn & 1;
    int tok0 = b * SEQ + cn * 32;
    int row = lane >> 3, s8 = lane & 7;
    int sx = ((s8 ^ (row & 7)) * 8);
    {
      int p = (wid < 4) ? wid : wid - 4;
      int colbase = (wid < 4) ? (1024 + h * 64) : (h * 64);
      int off = (wid < 4) ? D_OFF_K : D_OFF_Q;
      const unsigned short* src = qkv + (size_t)(tok0 + p * 8 + row) * 3072 + colbase + sx;
      unsigned short* dst = (unsigned short*)(smem + off + buf * 4096 + p * 1024) + lane * 8;
      __builtin_amdgcn_global_load_lds(
          (const __attribute__((address_space(1))) unsigned int*)src,
          (__attribute__((address_space(3))) unsigned int*)dst, 16, 0, 0);
    }
    if (wid < 4) {
      int p = wid;
      const unsigned short* src = qkv + (size_t)(tok0 + p * 8 + row) * 3072 + 2048 + h * 64 + sx;
      unsigned short* dst = (unsigned short*)(smem + D_OFF_V + buf * 4096 + p * 1024) + lane * 8;
      __builtin_amdgcn_global_load_lds(
          (const __attribute__((address_space(1))) unsigned int*)src,
          (__attribute__((address_space(3))) unsigned int*)dst, 16, 0, 0);
    }
  };

  auto ab_compute = [&](int cn) {
    int t = lane & 31;
    int tok = b * SEQ + cn * 32 + t;
    float av = alphaF[(size_t)tok * 16 + h];
    float bv = betaF[(size_t)tok * 16 + h];
    float p = av;
#pragma unroll
    for (int s = 1; s < 32; s <<= 1) {
      float o = __shfl_up(p, s, 32);
      if ((lane & 31) >= s) p *= o;
    }
    float ep = __shfl_up(p, 1, 32);
    if ((lane & 31) == 0) ep = 1.f;
    float* ap = abf + (cn & 3) * 132;
    if (lane < 32) {
      ap[0 + t] = ep;          // eprev
      ap[32 + t] = p;          // einc
      ap[64 + t] = 1.0f / p;   // einv
      if (t == 31) ap[128] = p;
    } else {
      ap[96 + t] = bv;         // b
    }
  };

  auto gram_do = [&](int cn) {
    // waves 3,4: KK -> Mt ; waves 5,6: KQ -> Gbf
    if (wid < 3 || wid > 6) return;
    int buf = cn & 1;
    const char* Kn = smem + D_OFF_K + buf * 4096;
    const char* Qn = smem + D_OFF_Q + buf * 4096;
    const float* ap = abf + (cn & 3) * 132;
    bool kk = (wid <= 4);
    int g0 = (kk ? (wid - 3) : (wid - 5)) * 2;
#pragma unroll
    for (int j = 0; j < 2; ++j) {
      int g = g0 + j, gi = g >> 1, gt = g & 1;
      f32x4 acc = (f32x4){0.f, 0.f, 0.f, 0.f};
#pragma unroll
      for (int ks = 0; ks < 2; ++ks) {
        int o = ks * 64 + qd * 16;
        bf16x8s af = *(const bf16x8s*)(Kn + (gi * 16 + r) * 128 + (o ^ ((r & 7) << 4)));
        bf16x8s bf = kk
            ? *(const bf16x8s*)(Kn + (gt * 16 + r) * 128 + (o ^ ((r & 7) << 4)))
            : *(const bf16x8s*)(Qn + (gt * 16 + r) * 128 + (o ^ ((r & 7) << 4)));
        acc = __builtin_amdgcn_mfma_f32_16x16x32_bf16(af, bf, acc, 0, 0, 0);
      }
      int tl = gt * 16 + r;
      f32x4 ei4 = *(const f32x4*)&ap[64 + gi * 16 + qd * 4];
      if (kk) {
        float bt = ap[96 + tl], ept = ap[0 + tl];
        float* Mtp = (float*)(smem + D_OFF_MT + buf * 4096);
#pragma unroll
        for (int reg = 0; reg < 4; ++reg) {
          int i = gi * 16 + qd * 4 + reg;
          Mtp[i * 32 + tl] = (i < tl) ? bt * ept * ei4[reg] * acc[reg] : 0.f;
        }
      } else {
        float et = ap[32 + tl];
        unsigned short* Gp = (unsigned short*)(smem + D_OFF_GBF + buf * 2048);
#pragma unroll
        for (int reg = 0; reg < 4; ++reg) {
          int i = gi * 16 + qd * 4 + reg;
          float v = (i <= tl) ? et * ei4[reg] * acc[reg] : 0.f;
          Gp[tl * 32 + i] = f2bf(v);
        }
      }
    }
  };

  // S master in registers: tiles s = wid*2 + j, j in {0,1}; per tile 4 rows (qd*4+reg)
  float sreg[8];
#pragma unroll
  for (int i = 0; i < 8; ++i) sreg[i] = 0.f;

  // ---------------- prologue ----------------
  {
    uint4 z = (uint4){0u, 0u, 0u, 0u};
    *(uint4*)(smem + D_OFF_STHI + tid * 16) = z;
    *(uint4*)(smem + D_OFF_STLO + tid * 16) = z;
  }
  stage_jobs(0);
  if (wid == 0) ab_compute(0);
  else if (wid == 1) ab_compute(1);
  __syncthreads();
  gram_do(0);
  __syncthreads();

  const char* SThi = smem + D_OFF_STHI;
  const char* STlo = smem + D_OFF_STLO;

  for (int c = 0; c < 64; ++c) {
    const int cbuf = c & 1, cs = c & 3;
    // -------- phase 1: stage(c+1) + W(c) + Y(c-1) --------
    if (c + 1 < 64) stage_jobs(c + 1);
    {
      // W = K(c) * S_in  (hi+lo)
      int tt = wid >> 2, te = wid & 3;
      const char* Kc = smem + D_OFF_K + cbuf * 4096;
      f32x4 acc = (f32x4){0.f, 0.f, 0.f, 0.f};
#pragma unroll
      for (int ks = 0; ks < 2; ++ks) {
        int o = ks * 64 + qd * 16;
        bf16x8s af = *(const bf16x8s*)(Kc + (tt * 16 + r) * 128 + (o ^ ((r & 7) << 4)));
        bf16x8s bhv = *(const bf16x8s*)(SThi + (te * 16 + r) * 128 + (o ^ ((r & 7) << 4)));
        bf16x8s blv = *(const bf16x8s*)(STlo + (te * 16 + r) * 128 + (o ^ ((r & 7) << 4)));
        acc = __builtin_amdgcn_mfma_f32_16x16x32_bf16(af, bhv, acc, 0, 0, 0);
        acc = __builtin_amdgcn_mfma_f32_16x16x32_bf16(af, blv, acc, 0, 0, 0);
      }
      float* Wp = (float*)(smem + D_OFF_W);
#pragma unroll
      for (int reg = 0; reg < 4; ++reg)
        Wp[(tt * 16 + qd * 4 + reg) * 64 + te * 16 + r] = acc[reg];
    }
    if (c >= 1) {
      // Y(c-1) = diag(einc)*U + G*C
      int cc = c - 1, buf = cc & 1;
      int ty = wid >> 2, te = wid & 3;
      const char* Gp = smem + D_OFF_GBF + buf * 2048;
      bf16x8s af = *(const bf16x8s*)(Gp + (ty * 16 + r) * 64 + qd * 16);
      bf16x8s bhv = *(const bf16x8s*)(smem + D_OFF_CTHI + buf * 5120 + (te * 16 + r) * 80 + qd * 16);
      bf16x8s blv = *(const bf16x8s*)(smem + D_OFF_CTLO + buf * 5120 + (te * 16 + r) * 80 + qd * 16);
      f32x4 acc = (f32x4){0.f, 0.f, 0.f, 0.f};
      acc = __builtin_amdgcn_mfma_f32_16x16x32_bf16(af, bhv, acc, 0, 0, 0);
      acc = __builtin_amdgcn_mfma_f32_16x16x32_bf16(af, blv, acc, 0, 0, 0);
      const float* Up = (const float*)(smem + D_OFF_U + buf * 8192);
      f32x4 e4 = *(const f32x4*)&abf[(cc & 3) * 132 + 32 + ty * 16 + qd * 4];
#pragma unroll
      for (int reg = 0; reg < 4; ++reg) {
        int t = ty * 16 + qd * 4 + reg, e = te * 16 + r;
        float yv = fmaf(e4[reg], Up[t * 64 + e], acc[reg]);
        y[(size_t)(b * SEQ + cc * 32 + t) * 1024 + h * 64 + e] = f2bf(yv);
      }
    }
    __syncthreads();

    // -------- phase 2: fwd-sub | U | Gram(c+1) | KT | ab(c+2) --------
    if (wid == 0) {
      // forward substitution, lanes = e
      const float* Wp = (const float*)(smem + D_OFF_W);
      const char* Vb = smem + D_OFF_V + cbuf * 4096;
      const float* ap = abf + cs * 132;
      float vb = ap[96 + (lane & 31)];
      float vep = ap[0 + (lane & 31)];
      float d_[32], r_[32];
#pragma unroll
      for (int i = 0; i < 32; ++i) r_[i] = 0.f;
#pragma unroll
      for (int i = 0; i < 32; ++i) {
        float w = Wp[i * 64 + lane];
        unsigned short vx = *(const unsigned short*)(Vb + (i * 128 + ((lane * 2) ^ ((i & 7) << 4))));
        d_[i] = rdlane(vb, i) * fmaf(-rdlane(vep, i), w, bf2f(vx));
      }
      const float* Mtp = (const float*)(smem + D_OFF_MT + cbuf * 4096);
#pragma unroll
      for (int i = 0; i < 32; ++i) {
        float cv = d_[i] - r_[i];
        d_[i] = cv;
#pragma unroll
        for (int cb4 = 0; cb4 < 8; ++cb4) {
          if (cb4 * 4 + 3 > i) {  // skip chunks fully masked (compile-time)
            f32x4 m4 = *(const f32x4*)&Mtp[i * 32 + cb4 * 4];
            r_[cb4 * 4 + 0] = fmaf(m4[0], cv, r_[cb4 * 4 + 0]);
            r_[cb4 * 4 + 1] = fmaf(m4[1], cv, r_[cb4 * 4 + 1]);
            r_[cb4 * 4 + 2] = fmaf(m4[2], cv, r_[cb4 * 4 + 2]);
            r_[cb4 * 4 + 3] = fmaf(m4[3], cv, r_[cb4 * 4 + 3]);
          }
        }
      }
      // pack C -> hi/lo bf16, row e, 32 cols
      unsigned int ph[16], pl[16];
#pragma unroll
      for (int j = 0; j < 16; ++j) {
        unsigned short h0 = f2bf(d_[2 * j]), h1 = f2bf(d_[2 * j + 1]);
        ph[j] = (unsigned int)h0 | ((unsigned int)h1 << 16);
        float l0 = d_[2 * j] - bf2f(h0), l1 = d_[2 * j + 1] - bf2f(h1);
        pl[j] = (unsigned int)f2bf(l0) | ((unsigned int)f2bf(l1) << 16);
      }
      char* Ch = smem + D_OFF_CTHI + cbuf * 5120 + lane * 80;
      char* Cl = smem + D_OFF_CTLO + cbuf * 5120 + lane * 80;
#pragma unroll
      for (int k = 0; k < 4; ++k) {
        *(uint4*)(Ch + k * 16) = (uint4){ph[4 * k], ph[4 * k + 1], ph[4 * k + 2], ph[4 * k + 3]};
        *(uint4*)(Cl + k * 16) = (uint4){pl[4 * k], pl[4 * k + 1], pl[4 * k + 2], pl[4 * k + 3]};
      }
    } else {
      if (wid <= 4) {
        // U = Q(c) * S_in : tiles (wid-1)*2, +1
        const char* Qc = smem + D_OFF_Q + cbuf * 4096;
        float* Up = (float*)(smem + D_OFF_U + cbuf * 8192);
#pragma unroll
        for (int j = 0; j < 2; ++j) {
          int u = (wid - 1) * 2 + j, tu = u >> 2, te = u & 3;
          f32x4 acc = (f32x4){0.f, 0.f, 0.f, 0.f};
#pragma unroll
          for (int ks = 0; ks < 2; ++ks) {
            int o = ks * 64 + qd * 16;
            bf16x8s af = *(const bf16x8s*)(Qc + (tu * 16 + r) * 128 + (o ^ ((r & 7) << 4)));
            bf16x8s bhv = *(const bf16x8s*)(SThi + (te * 16 + r) * 128 + (o ^ ((r & 7) << 4)));
            bf16x8s blv = *(const bf16x8s*)(STlo + (te * 16 + r) * 128 + (o ^ ((r & 7) << 4)));
            acc = __builtin_amdgcn_mfma_f32_16x16x32_bf16(af, bhv, acc, 0, 0, 0);
            acc = __builtin_amdgcn_mfma_f32_16x16x32_bf16(af, blv, acc, 0, 0, 0);
          }
#pragma unroll
          for (int reg = 0; reg < 4; ++reg)
            Up[(tu * 16 + qd * 4 + reg) * 64 + te * 16 + r] = acc[reg];
        }
      }
      if (c + 1 < 64) gram_do(c + 1);
      if (wid == 7) {
        // KT'[d][i] = K[i][d] * e31 * einv[i]
        const float* ap = abf + cs * 132;
        float vei = ap[64 + (lane & 31)];
        float e31 = ap[128];
        const char* Kc = smem + D_OFF_K + cbuf * 4096;
        unsigned short* KT = (unsigned short*)(smem + D_OFF_KT);
        unsigned int pk[16];
#pragma unroll
        for (int i = 0; i < 32; ++i) {
          unsigned short kv = *(const unsigned short*)(Kc + (i * 128 + ((lane * 2) ^ ((i & 7) << 4))));
          float f = bf2f(kv) * (e31 * rdlane(vei, i));
          unsigned short o = f2bf(f);
          if (i & 1) pk[i >> 1] |= ((unsigned int)o << 16);
          else       pk[i >> 1] = o;
        }
#pragma unroll
        for (int k = 0; k < 4; ++k)
          *(uint4*)((char*)KT + lane * 64 + k * 16) =
              (uint4){pk[4 * k], pk[4 * k + 1], pk[4 * k + 2], pk[4 * k + 3]};
      }
      if (wid == 2 && c + 2 < 64) ab_compute(c + 2);
    }
    __syncthreads();

    // -------- phase 3: S_out = e31*S + KT' * C --------
    {
      float e31 = abf[cs * 132 + 128];
      const char* KT = smem + D_OFF_KT;
#pragma unroll
      for (int j = 0; j < 2; ++j) {
        int s = wid * 2 + j, td = s >> 2, te = s & 3;
        bf16x8s af = *(const bf16x8s*)(KT + (td * 16 + r) * 64 + qd * 16);
        bf16x8s bhv = *(const bf16x8s*)(smem + D_OFF_CTHI + cbuf * 5120 + (te * 16 + r) * 80 + qd * 16);
        bf16x8s blv = *(const bf16x8s*)(smem + D_OFF_CTLO + cbuf * 5120 + (te * 16 + r) * 80 + qd * 16);
        f32x4 acc = (f32x4){0.f, 0.f, 0.f, 0.f};
        acc = __builtin_amdgcn_mfma_f32_16x16x32_bf16(af, bhv, acc, 0, 0, 0);
        acc = __builtin_amdgcn_mfma_f32_16x16x32_bf16(af, blv, acc, 0, 0, 0);
#pragma unroll
        for (int reg = 0; reg < 4; ++reg) {
          int d = td * 16 + qd * 4 + reg, e = te * 16 + r;
          float sv = fmaf(e31, sreg[j * 4 + reg], acc[reg]);
          sreg[j * 4 + reg] = sv;
          unsigned short hi = f2bf(sv);
          float lo = sv - bf2f(hi);
          *(unsigned short*)(smem + D_OFF_STHI + e * 128 + ((d * 2) ^ ((e & 7) << 4))) = hi;
          *(unsigned short*)(smem + D_OFF_STLO + e * 128 + ((d * 2) ^ ((e & 7) << 4))) = f2bf(lo);
        }
      }
    }
    __syncthreads();
  }

  // -------- epilogue: Y(63) --------
  {
    int cc = 63, buf = cc & 1;
    int ty = wid >> 2, te = wid & 3;
    const char* Gp = smem + D_OFF_GBF + buf * 2048;
    bf16x8s af = *(const bf16x8s*)(Gp + (ty * 16 + r) * 64 + qd * 16);
    bf16x8s bhv = *(const bf16x8s*)(smem + D_OFF_CTHI + buf * 5120 + (te * 16 + r) * 80 + qd * 16);
    bf16x8s blv = *(const bf16x8s*)(smem + D_OFF_CTLO + buf * 5120 + (te * 16 + r) * 80 + qd * 16);
    f32x4 acc = (f32x4){0.f, 0.f, 0.f, 0.f};
    acc = __builtin_amdgcn_mfma_f32_16x16x32_bf16(af, bhv, acc, 0, 0, 0);
    acc = __builtin_amdgcn_mfma_f32_16x16x32_bf16(af, blv, acc, 0, 0, 0);
    const float* Up = (const float*)(smem + D_OFF_U + buf * 8192);
    f32x4 e4 = *(const f32x4*)&abf[(cc & 3) * 132 + 32 + ty * 16 + qd * 4];
#pragma unroll
    for (int reg = 0; reg < 4; ++reg) {
      int t = ty * 16 + qd * 4 + reg, e = te * 16 + r;
      float yv = fmaf(e4[reg], Up[t * 64 + e], acc[reg]);
      y[(size_t)(b * SEQ + cc * 32 + t) * 1024 + h * 64 + e] = f2bf(yv);
    }
  }
}

// ---------------------------------------------------------------- rmsnorm*gate
__global__ __launch_bounds__(256) void rmsgate_k(const unsigned short* __restrict__ y,
                                                 const unsigned short* __restrict__ gl,
                                                 const float* __restrict__ gnorm,
                                                 unsigned short* __restrict__ z) {
  __shared__ float red[4];
  int row = blockIdx.x, tid = threadIdx.x;
  size_t base = (size_t)row * 1024 + tid * 4;
  uint2 yv = *(const uint2*)&y[base];
  float f0 = bf2f((unsigned short)(yv.x & 0xffff)), f1 = bf2f((unsigned short)(yv.x >> 16));
  float f2 = bf2f((unsigned short)(yv.y & 0xffff)), f3 = bf2f((unsigned short)(yv.y >> 16));
  float ss = f0 * f0 + f1 * f1 + f2 * f2 + f3 * f3;
#pragma unroll
  for (int s = 1; s < 64; s <<= 1) ss += __shfl_xor(ss, s);
  if ((tid & 63) == 0) red[tid >> 6] = ss;
  __syncthreads();
  ss = red[0] + red[1] + red[2] + red[3];
  float rms = rsqrtf(ss * (1.0f / 1024.0f) + 1e-5f);
  uint2 gv = *(const uint2*)&gl[base];
  float4 gn = *(const float4*)&gnorm[tid * 4];
  float g[4] = {bf2f((unsigned short)(gv.x & 0xffff)), bf2f((unsigned short)(gv.x >> 16)),
                bf2f((unsigned short)(gv.y & 0xffff)), bf2f((unsigned short)(gv.y >> 16))};
  float gnv[4] = {gn.x, gn.y, gn.z, gn.w};
  float fv[4] = {f0, f1, f2, f3};
  unsigned short o[4];
#pragma unroll
  for (int jj = 0; jj < 4; jj++) {
    float gate = g[jj] / (1.f + expf(-g[jj]));
    o[jj] = f2bf(fv[jj] * rms * gnv[jj] * gate);
  }
  uint2 ov;
  ov.x = (unsigned int)o[0] | ((unsigned int)o[1] << 16);
  ov.y = (unsigned int)o[2] | ((unsigned int)o[3] << 16);
  *(uint2*)&z[base] = ov;
}

// ---------------------------------------------------------------- launch
extern "C" void kernel_launch(void* const* d_in, const int* in_sizes, int n_in,
                              void* d_out, int out_size, void* d_ws, size_t ws_size,
                              hipStream_t stream) {
  const float* x     = (const float*)d_in[0];
  const float* Wq    = (const float*)d_in[1];
  const float* Wk    = (const float*)d_in[2];
  const float* Wv    = (const float*)d_in[3];
  const float* Wa    = (const float*)d_in[4];
  const float* ba    = (const float*)d_in[5];
  const float* Wb    = (const float*)d_in[6];
  const float* bb    = (const float*)d_in[7];
  const float* Wg    = (const float*)d_in[8];
  const float* Wo    = (const float*)d_in[9];
  const float* gnorm = (const float*)d_in[10];
  float* out = (float*)d_out;

  unsigned short* xbf    = (unsigned short*)d_ws;                 // 8192*1024
  unsigned short* Bt_qkv = xbf + (size_t)NTOK * 1024;             // 3200*1024
  unsigned short* Bt_g   = Bt_qkv + (size_t)NQKV * 1024;          // 1024*1024
  unsigned short* Bt_o   = Bt_g + (size_t)1024 * 1024;            // 1024*1024
  unsigned short* qkv    = Bt_o + (size_t)1024 * 1024;            // 8192*3072
  unsigned short* gatelin= qkv + (size_t)NTOK * 3072;             // 8192*1024
  unsigned short* ybuf   = gatelin + (size_t)NTOK * 1024;         // 8192*1024
  float* alphaF          = (float*)(ybuf + (size_t)NTOK * 1024);  // 8192*16
  float* betaF           = alphaF + (size_t)NTOK * 16;            // 8192*16
  unsigned short* zbuf   = xbf;  // alias: xbf dead after gate GEMM

  static int dscan_inited = 0;
  if (!dscan_inited) {
    hipFuncSetAttribute((const void*)dscan_k,
                        hipFuncAttributeMaxDynamicSharedMemorySize, D_LDS_SIZE);
    dscan_inited = 1;
  }

  castx_k<<<NTOK * 1024 / 4 / 256, 256, 0, stream>>>(x, xbf, NTOK * 1024 / 4);
  dim3 tb(32, 8);
  transpose_k<<<dim3(32, 32), tb, 0, stream>>>(Wq, Bt_qkv, 1024, 1024);
  transpose_k<<<dim3(32, 32), tb, 0, stream>>>(Wk, Bt_qkv + (size_t)1024 * 1024, 1024, 1024);
  transpose_k<<<dim3(32, 32), tb, 0, stream>>>(Wv, Bt_qkv + (size_t)2048 * 1024, 1024, 1024);
  transpose_k<<<dim3(32, 32), tb, 0, stream>>>(Wg, Bt_g, 1024, 1024);
  transpose_k<<<dim3(32, 32), tb, 0, stream>>>(Wo, Bt_o, 1024, 1024);
  build_wabT<<<512, 256, 0, stream>>>(Wa, Wb, Bt_qkv + (size_t)3072 * 1024);

  gemm_bt<2><<<(NTOK / 128) * (NQKV / 128), 256, 0, stream>>>(
      xbf, Bt_qkv, qkv, NTOK, NQKV, 1024, ba, bb, alphaF, betaF);
  gemm_bt<0><<<(NTOK / 128) * (1024 / 128), 256, 0, stream>>>(
      xbf, Bt_g, gatelin, NTOK, 1024, 1024, nullptr, nullptr, nullptr, nullptr);
  dscan_k<<<64, 512, D_LDS_SIZE, stream>>>(qkv, alphaF, betaF, ybuf);
  rmsgate_k<<<NTOK, 256, 0, stream>>>(ybuf, gatelin, gnorm, zbuf);
  gemm_bt<1><<<(NTOK / 128) * (1024 / 128), 256, 0, stream>>>(
      zbuf, Bt_o, out, NTOK, 1024, 1024, nullptr, nullptr, nullptr, nullptr);
}